// Round 10
// baseline (195.565 us; speedup 1.0000x reference)
//
#include <hip/hip_runtime.h>
#include <cstdint>
#include <cstddef>

// Problem shape (fixed by setup_inputs): hidden [4,2048,2048] -> M=8192, K=2048, N=2048
#define MDIM 8192
#define NDIM 2048
#define KDIM 2048

constexpr int BM = 128, BN = 256, BK = 64;   // dbuf: 2 x (8KB A + 16KB B) = 48 KB -> 2 blocks/CU

typedef int v4i __attribute__((ext_vector_type(4)));

__device__ __forceinline__ void async_ld16(const void* g, void* l) {
    __builtin_amdgcn_global_load_lds(
        (const __attribute__((address_space(1))) int*)g,
        (__attribute__((address_space(3))) int*)l,
        16, 0, 0);
}

// quantize: clamp(round(x/s), -127, 127) — matches jnp.round (rne) + clip; verified absmax 0
__device__ __forceinline__ uint32_t q8(float x, float inv) {
    float q = fminf(fmaxf(rintf(x * inv), -127.f), 127.f);
    return (uint32_t)((int)q) & 0xffu;
}
__device__ __forceinline__ uint32_t q8x4(float4 v, float inv) {
    return q8(v.x, inv) | (q8(v.y, inv) << 8) | (q8(v.z, inv) << 16) | (q8(v.w, inv) << 24);
}

// ---------- W quant + transpose: fp32 [K][N] -> int8 [N][K] (x-quant is fused into GEMM) ----------
__global__ void quant_w_kernel(const float* __restrict__ w, uint32_t* __restrict__ wt) {
    __shared__ uint32_t t[64][17];
    const int tid = threadIdx.x;
    const int bid = blockIdx.x;                    // 0..1023
    const int k0 = (bid >> 5) * 64;                // KDIM/64 = 32
    const int n0 = (bid & 31) * 64;                // NDIM/64 = 32
    const int rr  = tid >> 4;                      // 0..15
    const int c4  = (tid & 15) * 4;                // 0..60
#pragma unroll
    for (int p = 0; p < 4; ++p) {
        int r = rr + p * 16;
        float4 v = *(const float4*)&w[(size_t)(k0 + r) * NDIM + n0 + c4];
        uint32_t pk = (uint32_t)((int)rintf(v.x) & 0xff)
                    | ((uint32_t)((int)rintf(v.y) & 0xff) << 8)
                    | ((uint32_t)((int)rintf(v.z) & 0xff) << 16)
                    | ((uint32_t)((int)rintf(v.w) & 0xff) << 24);
        t[r][c4 >> 2] = pk;
    }
    __syncthreads();
    // read side: thread owns column c = rr+p*16, rows c4..c4+3 -> one uint32 out
#pragma unroll
    for (int p = 0; p < 4; ++p) {
        int c = rr + p * 16;
        uint32_t o = 0;
#pragma unroll
        for (int j = 0; j < 4; ++j) {
            uint32_t b = (t[c4 + j][c >> 2] >> ((c & 3) * 8)) & 0xffu;
            o |= b << (j * 8);
        }
        wt[((size_t)(n0 + c) * KDIM + k0 + c4) >> 2] = o;
    }
}

// ---------- fused GEMM: C = quant(X) * Bt^T + bias; A quantized on the fly ----------
// R7 structure (best: 48 us) with A-staging switched from async-int8 to reg-staged
// fp32 load -> quantize -> ds_write into the IDENTICAL LDS layout (slot lane&3 holds
// global chunk (lane&3)^((srow>>1)&3); read side byte-identical to R7, 0 conflicts).
// Register envelope (unified VGPR+AGPR, cap 128 at (512,4); R7 sat at exactly 64+64):
// COMPUTE uses i-loop fragment form (bf[4] + 1 af live) to make room for 16 a-regs.
// X (64 MB fp32) fits L3; n-fastest XCD swizzle makes the 8x A-panel re-read L2/L3-hit.
__global__ __launch_bounds__(512, 4)
void gemm_i8_kernel(const float* __restrict__ X,   // [M][K] fp32 (integer after scale)
                    const int8_t* __restrict__ Bt, // [N][K] int8
                    const float* __restrict__ scale_p,
                    const float* __restrict__ bias, // [N]
                    float* __restrict__ C) {        // [M][N] fp32
    __shared__ alignas(16) int8_t lA[2][BM * BK];   // 2 x 8 KB
    __shared__ alignas(16) int8_t lB[2][BN * BK];   // 2 x 16 KB

    const int tid  = threadIdx.x;
    const int lane = tid & 63;
    const int wave = tid >> 6;           // 0..7
    const int wm   = wave & 1;           // M-half: 64 rows
    const int wn   = wave >> 1;          // N-quarter: 64 cols

    // XCD-aware bijective swizzle: 512 blocks -> 64 per XCD = 8 m-panels x 8 n-panels,
    // n fastest so co-resident blocks on one XCD share the same A-panel.
    const int bidlin = blockIdx.y * gridDim.x + blockIdx.x;   // 0..511
    const int xcd    = bidlin & 7;
    const int idx    = bidlin >> 3;                            // 0..63
    const int m0     = (xcd * 8 + (idx >> 3)) * BM;            // 64 m-panels
    const int n0     = (idx & 7) * BN;                         // 8 n-panels

    // staging: A wave covers rows [wave*16,+16) reg-staged; B wave covers [wave*32,+32) async
    const int srow = lane >> 2;                       // 0..15
    const int schk = (lane & 3) ^ ((srow >> 1) & 3);  // swizzled source chunk
    const float*  gA = X  + (size_t)(m0 + wave * 16 + srow) * KDIM + schk * 16;
    const int8_t* gB = Bt + (size_t)(n0 + wave * 32 + srow) * KDIM + schk * 16;
    const int lwoA = wave * 1024;
    const int lwoB = wave * 2048;

    // fragments: lane reads row (.. + lr), global chunk quad -> LDS chunk quad^((lr>>1)&3)
    const int quad = lane >> 4;
    const int lr   = lane & 15;
    const int fchk = (quad ^ ((lr >> 1) & 3)) * 16;
    const int aoff = (wm * 64 + lr) * BK + fchk;
    const int boff = (wn * 64 + lr) * BK + fchk;

    const float inv = 1.0f / fmaxf(scale_p[0], 1e-8f);

    v4i acc[4][4];
#pragma unroll
    for (int i = 0; i < 4; ++i)
#pragma unroll
        for (int j = 0; j < 4; ++j)
            acc[i][j] = (v4i){0, 0, 0, 0};

    float4 a0, a1, a2, a3;               // in-flight A chunk (16 fp32 = one 16B LDS slot)

#define A_LOAD(kof)                                                            \
    do {                                                                       \
        const float4* p = (const float4*)(gA + (kof));                         \
        a0 = p[0]; a1 = p[1]; a2 = p[2]; a3 = p[3];                            \
    } while (0)

    // compiler auto-inserts the counted vmcnt wait before the a0..a3 uses
#define A_WRITE(buf)                                                           \
    do {                                                                       \
        v4i pk = { (int)q8x4(a0, inv), (int)q8x4(a1, inv),                     \
                   (int)q8x4(a2, inv), (int)q8x4(a3, inv) };                   \
        *(v4i*)&lA[buf][lwoA + lane * 16] = pk;                                \
    } while (0)

#define STAGE_B(buf, kof)                                                      \
    do {                                                                       \
        async_ld16(gB + (kof), &lB[buf][lwoB]);                                \
        async_ld16(gB + (kof) + (size_t)16 * KDIM, &lB[buf][lwoB + 1024]);     \
    } while (0)

#define COMPUTE(buf)                                                           \
    do {                                                                       \
        v4i bf[4];                                                             \
        _Pragma("unroll")                                                      \
        for (int j = 0; j < 4; ++j)                                            \
            bf[j] = *(const v4i*)&lB[buf][boff + j * 1024];                    \
        _Pragma("unroll")                                                      \
        for (int i = 0; i < 4; ++i) {                                          \
            v4i af = *(const v4i*)&lA[buf][aoff + i * 1024];                   \
            _Pragma("unroll")                                                  \
            for (int j = 0; j < 4; ++j)                                        \
                acc[i][j] = __builtin_amdgcn_mfma_i32_16x16x64_i8(             \
                    af, bf[j], acc[i][j], 0, 0, 0);                            \
        }                                                                      \
    } while (0)

    // prologue: tile 0 — A regs + B asyncs; quantize+write A0 (waits only the 4 A loads)
    A_LOAD(0);
    STAGE_B(0, 0);
    A_WRITE(0);
    int kof = BK;
    for (int it = 0; it < KDIM / BK - 1; ++it) {
        __syncthreads();                 // drains B asyncs (tile it visible); orders A writes
        A_LOAD(kof);                     // issue next A tile early (covered by COMPUTE)
        STAGE_B((it + 1) & 1, kof);      // next B tile flies across the loop
        asm volatile("" ::: "memory");   // pin loads/asyncs before COMPUTE's ds_reads
        COMPUTE(it & 1);
        A_WRITE((it + 1) & 1);           // quantize + ds_write; buf free (readers done pre-barrier)
        kof += BK;
    }
    __syncthreads();
    COMPUTE((KDIM / BK - 1) & 1);

#undef A_LOAD
#undef A_WRITE
#undef STAGE_B
#undef COMPUTE

    // epilogue: C/D layout col = lane&15, row = quad*4 + reg (verified, dtype-indep)
    const int crow = m0 + wm * 64 + quad * 4;
    const int ccol = n0 + wn * 64 + lr;
    float bj[4];
#pragma unroll
    for (int j = 0; j < 4; ++j) bj[j] = bias[ccol + j * 16];
#pragma unroll
    for (int i = 0; i < 4; ++i)
#pragma unroll
        for (int j = 0; j < 4; ++j)
#pragma unroll
            for (int r = 0; r < 4; ++r)
                C[(size_t)(crow + i * 16 + r) * NDIM + (ccol + j * 16)] = (float)acc[i][j][r] + bj[j];
}

extern "C" void kernel_launch(void* const* d_in, const int* in_sizes, int n_in,
                              void* d_out, int out_size, void* d_ws, size_t ws_size,
                              hipStream_t stream) {
    const float* x    = (const float*)d_in[0];   // [8192, 2048] fp32
    const float* w    = (const float*)d_in[1];   // [2048, 2048] fp32 (integer-valued)
    const float* xs   = (const float*)d_in[2];   // scalar
    const float* bias = (const float*)d_in[3];   // [2048]
    float* out = (float*)d_out;                  // [8192, 2048] fp32

    int8_t* wt = (int8_t*)d_ws;                  // 4 MB (xq eliminated — fused into GEMM)

    quant_w_kernel<<<(KDIM / 64) * (NDIM / 64), 256, 0, stream>>>(w, (uint32_t*)wt);
    gemm_i8_kernel<<<dim3(NDIM / BN, MDIM / BM), 512, 0, stream>>>(x, wt, xs, bias, out);
}

// Round 11
// 163.366 us; speedup vs baseline: 1.1971x; 1.1971x over previous
//
#include <hip/hip_runtime.h>
#include <cstdint>
#include <cstddef>

// Problem shape (fixed by setup_inputs): hidden [4,2048,2048] -> M=8192, K=2048, N=2048
#define MDIM 8192
#define NDIM 2048
#define KDIM 2048

constexpr int BM = 128, BN = 256, BK = 64;   // dbuf: 2 x (8KB A + 16KB B) = 48 KB -> 2 blocks/CU

typedef int v4i __attribute__((ext_vector_type(4)));

__device__ __forceinline__ void async_ld16(const void* g, void* l) {
    __builtin_amdgcn_global_load_lds(
        (const __attribute__((address_space(1))) int*)g,
        (__attribute__((address_space(3))) int*)l,
        16, 0, 0);
}

// ---------- fused quantize: x fp32 -> int8 (packed u32)  +  W fp32 [K][N] -> int8 [N][K] ----------
__device__ __forceinline__ uint32_t q8(float x, float inv) {
    float q = fminf(fmaxf(rintf(x * inv), -127.f), 127.f);
    return (uint32_t)((int)q) & 0xffu;
}

// W-part first (blocks 0..1023), then x-part: 4096 blocks x 256 threads x 4 chunked float4
#define WBLOCKS ((KDIM / 64) * (NDIM / 64))       // 1024
#define XCHUNK (MDIM * KDIM / 4 / 4)              // float4s per chunk = 1048576
#define XBLOCKS (XCHUNK / 256)                    // 4096 blocks

__global__ void quant_kernel(const float4* __restrict__ x, uint32_t* __restrict__ xq,
                             const float* __restrict__ scale_p,
                             const float* __restrict__ w, uint32_t* __restrict__ wt) {
    __shared__ uint32_t t[64][17];
    const int tid = threadIdx.x;

    if (blockIdx.x >= WBLOCKS) {
        // ---- x quant: thread handles 4 float4s at chunk stride (all accesses coalesced) ----
        int i = (blockIdx.x - WBLOCKS) * 256 + tid;
        float inv = 1.0f / fmaxf(scale_p[0], 1e-8f);
#pragma unroll
        for (int k = 0; k < 4; ++k) {
            float4 v = x[i + k * XCHUNK];
            xq[i + k * XCHUNK] =
                q8(v.x, inv) | (q8(v.y, inv) << 8) | (q8(v.z, inv) << 16) | (q8(v.w, inv) << 24);
        }
        return;
    }

    // ---- W quant + transpose: 64x64 tile per block ----
    const int bid = blockIdx.x;                    // 0..1023
    const int k0 = (bid >> 5) * 64;                // KDIM/64 = 32
    const int n0 = (bid & 31) * 64;                // NDIM/64 = 32
    const int rr  = tid >> 4;                      // 0..15
    const int c4  = (tid & 15) * 4;                // 0..60
#pragma unroll
    for (int p = 0; p < 4; ++p) {
        int r = rr + p * 16;
        float4 v = *(const float4*)&w[(size_t)(k0 + r) * NDIM + n0 + c4];
        uint32_t pk = (uint32_t)((int)rintf(v.x) & 0xff)
                    | ((uint32_t)((int)rintf(v.y) & 0xff) << 8)
                    | ((uint32_t)((int)rintf(v.z) & 0xff) << 16)
                    | ((uint32_t)((int)rintf(v.w) & 0xff) << 24);
        t[r][c4 >> 2] = pk;
    }
    __syncthreads();
    // read side: thread owns column c = rr+p*16, rows c4..c4+3 -> one uint32 out
#pragma unroll
    for (int p = 0; p < 4; ++p) {
        int c = rr + p * 16;
        uint32_t o = 0;
#pragma unroll
        for (int j = 0; j < 4; ++j) {
            uint32_t b = (t[c4 + j][c >> 2] >> ((c & 3) * 8)) & 0xffu;
            o |= b << (j * 8);
        }
        wt[((size_t)(n0 + c) * KDIM + k0 + c4) >> 2] = o;
    }
}

// ---------- i8 GEMM: C = A * Bt^T + bias; BM=128 x BN=256, 512 thr, R0 sync structure ----------
// Best measured config (R7/R9: gemm 45-48 us, MfmaUtil 28-30, FETCH 24.7 MB, 0 conflicts).
// launch_bounds(512,4): 128-VGPR cap (unified VGPR+AGPR file!) -> no spill, 2 blocks/CU.
// R6's (512,6) capped regs at ~85 < acc's 64+overhead -> 1 GB scratch spill. Never again.
// R8 (256^2, 16 waves/block) regressed: barrier lockstep cost beats staging savings past
// 8 waves/block. R10 (x-quant fused into A-staging) regressed 2x: 8 fp32 m-panels/XCD
// thrash the 4 MB L2, putting L3/HBM latency on the per-tile critical path. This shape
// is the family optimum. LDS row = 64B = 4 x 16B chunks; chunk c of row r stored at
// c ^ ((r>>1)&3) (verified SQ_LDS_BANK_CONFLICT == 0).
__global__ __launch_bounds__(512, 4)
void gemm_i8_kernel(const int8_t* __restrict__ A,   // [M][K] int8
                    const int8_t* __restrict__ Bt,  // [N][K] int8
                    const float* __restrict__ bias, // [N]
                    float* __restrict__ C) {        // [M][N] fp32
    __shared__ alignas(16) int8_t lA[2][BM * BK];   // 2 x 8 KB
    __shared__ alignas(16) int8_t lB[2][BN * BK];   // 2 x 16 KB

    const int tid  = threadIdx.x;
    const int lane = tid & 63;
    const int wave = tid >> 6;           // 0..7
    const int wm   = wave & 1;           // M-half: 64 rows
    const int wn   = wave >> 1;          // N-quarter: 64 cols

    // XCD-aware bijective swizzle: 512 blocks -> 64 per XCD = 8 m-panels x 8 n-panels,
    // n fastest so A-panels are shared by consecutive co-resident blocks on one XCD.
    const int bidlin = blockIdx.y * gridDim.x + blockIdx.x;   // 0..511
    const int xcd    = bidlin & 7;
    const int idx    = bidlin >> 3;                            // 0..63
    const int m0     = (xcd * 8 + (idx >> 3)) * BM;            // 64 m-panels
    const int n0     = (idx & 7) * BN;                         // 8 n-panels

    // staging: A wave covers rows [wave*16,+16) (1 issue); B wave covers [wave*32,+32) (2 issues)
    const int srow = lane >> 2;                       // 0..15
    const int schk = (lane & 3) ^ ((srow >> 1) & 3);  // swizzled source chunk
    const int8_t* gA = A  + (size_t)(m0 + wave * 16 + srow) * KDIM + schk * 16;
    const int8_t* gB = Bt + (size_t)(n0 + wave * 32 + srow) * KDIM + schk * 16;
    const int lwoA = wave * 1024;
    const int lwoB = wave * 2048;

    // fragments: lane reads row (.. + lr), global chunk quad -> LDS chunk quad^((lr>>1)&3)
    const int quad = lane >> 4;
    const int lr   = lane & 15;
    const int fchk = (quad ^ ((lr >> 1) & 3)) * 16;
    const int aoff = (wm * 64 + lr) * BK + fchk;
    const int boff = (wn * 64 + lr) * BK + fchk;

    v4i acc[4][4];
#pragma unroll
    for (int i = 0; i < 4; ++i)
#pragma unroll
        for (int j = 0; j < 4; ++j)
            acc[i][j] = (v4i){0, 0, 0, 0};

#define STAGE(buf, kof)                                                        \
    do {                                                                       \
        async_ld16(gA + (kof), &lA[buf][lwoA]);                                \
        async_ld16(gB + (kof), &lB[buf][lwoB]);                                \
        async_ld16(gB + (kof) + (size_t)16 * KDIM, &lB[buf][lwoB + 1024]);     \
    } while (0)

#define COMPUTE(buf)                                                           \
    do {                                                                       \
        v4i af[4], bf[4];                                                      \
        _Pragma("unroll")                                                      \
        for (int i = 0; i < 4; ++i)                                            \
            af[i] = *(const v4i*)&lA[buf][aoff + i * 1024];                    \
        _Pragma("unroll")                                                      \
        for (int j = 0; j < 4; ++j)                                            \
            bf[j] = *(const v4i*)&lB[buf][boff + j * 1024];                    \
        _Pragma("unroll")                                                      \
        for (int i = 0; i < 4; ++i)                                            \
            _Pragma("unroll")                                                  \
            for (int j = 0; j < 4; ++j)                                        \
                acc[i][j] = __builtin_amdgcn_mfma_i32_16x16x64_i8(             \
                    af[i], bf[j], acc[i][j], 0, 0, 0);                         \
    } while (0)

    STAGE(0, 0);
    int kof = BK;
    for (int it = 0; it < KDIM / BK - 1; ++it) {
        __syncthreads();                 // drains vmcnt: tile `it` visible; buf (it+1)&1 free
        STAGE((it + 1) & 1, kof);        // prefetch next tile (flies during compute)
        kof += BK;
        COMPUTE(it & 1);
    }
    __syncthreads();
    COMPUTE((KDIM / BK - 1) & 1);

    // epilogue: C/D layout col = lane&15, row = quad*4 + reg (verified, dtype-indep)
    const int crow = m0 + wm * 64 + quad * 4;
    const int ccol = n0 + wn * 64 + lr;
    float bj[4];
#pragma unroll
    for (int j = 0; j < 4; ++j) bj[j] = bias[ccol + j * 16];
#pragma unroll
    for (int i = 0; i < 4; ++i)
#pragma unroll
        for (int j = 0; j < 4; ++j)
#pragma unroll
            for (int r = 0; r < 4; ++r)
                C[(size_t)(crow + i * 16 + r) * NDIM + (ccol + j * 16)] = (float)acc[i][j][r] + bj[j];
}

extern "C" void kernel_launch(void* const* d_in, const int* in_sizes, int n_in,
                              void* d_out, int out_size, void* d_ws, size_t ws_size,
                              hipStream_t stream) {
    const float* x    = (const float*)d_in[0];   // [8192, 2048] fp32
    const float* w    = (const float*)d_in[1];   // [2048, 2048] fp32 (integer-valued)
    const float* xs   = (const float*)d_in[2];   // scalar
    const float* bias = (const float*)d_in[3];   // [2048]
    float* out = (float*)d_out;                  // [8192, 2048] fp32

    int8_t* xq = (int8_t*)d_ws;                          // 16 MB
    int8_t* wt = xq + (size_t)MDIM * KDIM;               //  4 MB

    quant_kernel<<<WBLOCKS + XBLOCKS, 256, 0, stream>>>(
        (const float4*)x, (uint32_t*)xq, xs, w, (uint32_t*)wt);
    gemm_i8_kernel<<<dim3(NDIM / BN, MDIM / BM), 512, 0, stream>>>(xq, wt, bias, out);
}